// Round 7
// baseline (1199.525 us; speedup 1.0000x reference)
//
#include <hip/hip_runtime.h>
#include <stdint.h>

#define N_NODES 50000
#define N_EDGES 800000
#define IN_C 64
#define HID 128
#define OUT_C 2
#define N_GRAPHS 64
#define NBUCK 196                    // ceil(N_NODES/256) buckets of 256 nodes
#define BCAP 6144                    // bucket capacity (mean 4096, sd ~64)
#define ECH 4096                     // edges per binA chunk (16 KB packed stage)
#define ASTR 36                      // agg LDS row stride (32 ch + 4 pad)

typedef long long i64;
typedef __attribute__((ext_vector_type(8))) short bf8;    // 8 bf16 = 4 VGPRs
typedef __attribute__((ext_vector_type(4))) float f32x4;  // MFMA C/D frag

__device__ __forceinline__ float bf2f(ushort h) {
    return __uint_as_float(((uint)h) << 16);
}
__device__ __forceinline__ ushort f2bf(float f) {
    uint x = __float_as_uint(f);
    uint r = x + 0x7fffu + ((x >> 16) & 1u);   // RNE
    return (ushort)(r >> 16);
}
__device__ __forceinline__ float loadf(const void* p, size_t i, int bf) {
    return bf ? bf2f(((const ushort*)p)[i]) : ((const float*)p)[i];
}
__device__ __forceinline__ int clampi(int v, int lo, int hi) {
    return min(max(v, lo), hi);
}
__device__ __forceinline__ int edge_src(const void* ei, int e, int wide) {
    return wide ? (int)((const i64*)ei)[e] : ((const int*)ei)[e];
}
__device__ __forceinline__ int edge_dst(const void* ei, int e, int wide) {
    return wide ? (int)((const i64*)ei)[N_EDGES + e] : ((const int*)ei)[N_EDGES + e];
}
__device__ __forceinline__ i64 batch_at(const void* b, int i, int wide) {
    return wide ? ((const i64*)b)[i] : (i64)((const int*)b)[i];
}
__device__ __forceinline__ uint pk2(float lo, float hi) {
    return ((uint)f2bf(hi) << 16) | (uint)f2bf(lo);
}

// ---- init: zero deg/bcnt/gbuf; block 0 also runs the dtype probes ----
__global__ __launch_bounds__(256) void k_init(const uint* __restrict__ braw,
                                              const uint* __restrict__ xraw,
                                              int* __restrict__ deg,
                                              int* __restrict__ bcnt,
                                              float* __restrict__ gbuf,
                                              int* __restrict__ iflag,
                                              int* __restrict__ fflag) {
    int i = blockIdx.x * blockDim.x + threadIdx.x;
    int stride = gridDim.x * blockDim.x;
    for (int j = i; j < N_NODES; j += stride) deg[j] = 0;
    if (i < N_GRAPHS * HID) gbuf[i] = 0.f;
    if (i < NBUCK) bcnt[i] = 0;
    if (blockIdx.x == 0) {
        __shared__ uint si[128];
        __shared__ int sf[256];
        int t = threadIdx.x;
        if (t < 128) si[t] = (t < 100) ? braw[25001 + 2 * t] : 0u;
        uint e = (xraw[t] >> 7) & 0xFFu;
        sf[t] = (e >= 100u && e <= 140u) ? 1 : 0;
        __syncthreads();
        for (int off = 128; off > 0; off >>= 1) {
            if (t < off) {
                sf[t] += sf[t + off];
                if (off <= 64 && t < 64) si[t] |= si[t + off];
            }
            __syncthreads();
        }
        if (t == 0) {
            *iflag = (si[0] == 0u) ? 1 : 0;   // 1 = int64, 0 = int32
            *fflag = (sf[0] >= 192) ? 1 : 0;  // 1 = bf16,  0 = f32
        }
    }
}

// ---- R23: degree histogram via no-return global atomics (50k ints, L2-hot).
// Blocks 0..95 also transpose W1/W2 to bf16 [HID][K]. ----
__global__ __launch_bounds__(256) void k_deg(const void* __restrict__ ei,
                                             const int* __restrict__ iflag,
                                             const int* __restrict__ fflag,
                                             const void* __restrict__ W1,
                                             const void* __restrict__ W2,
                                             ushort* __restrict__ Wt1,
                                             ushort* __restrict__ Wt2,
                                             int* __restrict__ deg) {
    int t = threadIdx.x;
    if (blockIdx.x < (IN_C * HID + HID * HID) / 256) {
        int ff = *fflag;
        int idx = blockIdx.x * 256 + t;
        if (idx < IN_C * HID) {
            int k = idx >> 7, n = idx & 127;
            Wt1[n * IN_C + k] = f2bf(loadf(W1, idx, ff));
        } else {
            int j = idx - IN_C * HID;
            int k = j >> 7, n = j & 127;
            Wt2[n * HID + k] = f2bf(loadf(W2, j, ff));
        }
    }
    int wide = *iflag;
    int i0 = blockIdx.x * 256 + t;
    int stride = gridDim.x * 256;
    for (int e = i0; e < N_EDGES; e += stride) {
        int d = edge_dst(ei, e, wide);
        atomicAdd(&deg[clampi(d, 0, N_NODES - 1)], 1);
    }
}

// ---- R23: dinv + Y1 = bf16(dinv*x) group-major [2][N][32] ----
__global__ __launch_bounds__(256) void k_prep(const int* __restrict__ deg,
                                              const void* __restrict__ x,
                                              const int* __restrict__ fflag,
                                              float* __restrict__ dinv,
                                              ushort* __restrict__ Y1) {
    int ff = *fflag;
    int i0 = blockIdx.x * 256 + (int)threadIdx.x;
    int stride = gridDim.x * 256;
    for (int n = i0; n < N_NODES; n += stride)
        dinv[n] = rsqrtf((float)(deg[n] + 1));
    for (int idx = i0; idx < N_NODES * (IN_C / 4); idx += stride) {
        int nn = idx >> 4, c4 = (idx & 15) * 4;
        float x0, x1, x2, x3;
        if (ff) {
            ushort4 u = *(const ushort4*)((const ushort*)x + (size_t)nn * IN_C + c4);
            x0 = bf2f(u.x); x1 = bf2f(u.y); x2 = bf2f(u.z); x3 = bf2f(u.w);
        } else {
            float4 vv = *(const float4*)((const float*)x + (size_t)nn * IN_C + c4);
            x0 = vv.x; x1 = vv.y; x2 = vv.z; x3 = vv.w;
        }
        float di = rsqrtf((float)(deg[nn] + 1));
        ushort4 o;
        o.x = f2bf(x0 * di); o.y = f2bf(x1 * di);
        o.z = f2bf(x2 * di); o.w = f2bf(x3 * di);
        int g = c4 >> 5;
        *(ushort4*)(Y1 + ((size_t)g * N_NODES + nn) * 32 + (c4 & 31)) = o;
    }
}

// ---- binA: bin edges by dst>>8 via LDS-sorted staging; contiguous runs.
// R23: edges packed into ONE uint (src:16 | dlocal:8 | bucket:8) — halves
// stage LDS and bmem traffic. 1024 threads/block. ----
__global__ __launch_bounds__(1024) void k_binA(const void* __restrict__ ei,
                                               const int* __restrict__ iflag,
                                               int* __restrict__ bcnt,
                                               uint* __restrict__ bmem) {
    int t = threadIdx.x;
    int wide = *iflag;
    __shared__ int cnt[NBUCK];
    __shared__ int obase[NBUCK];
    __shared__ int run[NBUCK];
    __shared__ int gbase[NBUCK];
    __shared__ int sc[256];
    __shared__ uint stage[ECH];
    int e0 = blockIdx.x * ECH;
    int m = min(ECH, N_EDGES - e0);
    for (int i = t; i < NBUCK; i += 1024) cnt[i] = 0;
    __syncthreads();
    for (int i = t; i < m; i += 1024) {
        int d = edge_dst(ei, e0 + i, wide);
        atomicAdd(&cnt[d >> 8], 1);
    }
    __syncthreads();
    int cv = (t < NBUCK) ? cnt[t] : 0;
    if (t < 256) sc[t] = cv;
    __syncthreads();
    for (int off = 1; off < 256; off <<= 1) {
        int v = (t >= off && t < 256) ? sc[t - off] : 0;
        __syncthreads();
        if (t < 256) sc[t] += v;
        __syncthreads();
    }
    if (t < NBUCK) {
        int ex = sc[t] - cv;
        obase[t] = ex;
        run[t] = ex;
        gbase[t] = (cv > 0) ? atomicAdd(&bcnt[t], cv) : 0;
    }
    __syncthreads();
    for (int i = t; i < m; i += 1024) {
        int s = edge_src(ei, e0 + i, wide);
        int d = edge_dst(ei, e0 + i, wide);
        int slot = atomicAdd(&run[d >> 8], 1);
        uint pr = (uint)clampi(s, 0, N_NODES - 1) |
                  ((uint)(d & 255) << 16) | ((uint)(d >> 8) << 24);
        stage[clampi(slot, 0, ECH - 1)] = pr;
    }
    __syncthreads();
    for (int i = t; i < m; i += 1024) {
        uint pr = stage[i];
        int b = (int)(pr >> 24);
        int pos = gbase[b] + (i - obase[b]);
        if (pos < BCAP) bmem[(size_t)b * BCAP + pos] = pr;
    }
}

// ---- R23: per-(bucket, channel-group) LDS scatter-accumulate aggregation.
// Replaces binB's counting sort + CSR + aggS entirely. agg[256][36] f32
// (padded: stride 36 rotates banks by 4/row). g = blockIdx&(GRP-1) keeps
// each XCD on one contiguous 3.2 MB source group (L2-resident).
// 8 lanes/edge read the 64 B group slice; ds_add_f32 into agg[dlocal]. ----
template <int LG>
__global__ __launch_bounds__(256) void k_agg(const ushort* __restrict__ src,
                                             const float* __restrict__ dinv,
                                             const int* __restrict__ bcnt,
                                             const uint* __restrict__ bmem,
                                             ushort* __restrict__ out) {
    const int GRP = 1 << LG;
    int g = blockIdx.x & (GRP - 1);
    int b = blockIdx.x >> LG;
    int tid = threadIdx.x;
    __shared__ float agg[256 * ASTR];
    for (int i = tid; i < 256 * ASTR; i += 256) agg[i] = 0.f;
    __syncthreads();
    int cnt = clampi(bcnt[b], 0, BCAP);
    const uint* eb = bmem + (size_t)b * BCAP;
    const uint2* sb = (const uint2*)(src + (size_t)g * N_NODES * 32);
    int l = tid & 7;          // channel slot: 8 B of the 64 B group slice
    int es = tid >> 3;        // edge slot: 32 edges in flight per block
    for (int i = es; i < cnt; i += 32) {
        uint e = eb[i];
        int s = min((int)(e & 0xFFFFu), N_NODES - 1);
        int dl = (int)((e >> 16) & 0xFFu);
        uint2 v = sb[(size_t)s * 8 + l];
        float* ap = &agg[dl * ASTR + l * 4];
        atomicAdd(ap + 0, bf2f((ushort)(v.x & 0xffffu)));
        atomicAdd(ap + 1, bf2f((ushort)(v.x >> 16)));
        atomicAdd(ap + 2, bf2f((ushort)(v.y & 0xffffu)));
        atomicAdd(ap + 3, bf2f((ushort)(v.y >> 16)));
    }
    __syncthreads();
    uint2* ob = (uint2*)(out + (size_t)g * N_NODES * 32);
    for (int idx = tid; idx < 256 * 8; idx += 256) {
        int node = idx >> 3, ll = idx & 7;
        int n = (b << 8) + node;
        if (n < N_NODES) {
            uint2 self = sb[(size_t)n * 8 + ll];
            float dv = dinv[n];
            const float* ap = &agg[node * ASTR + ll * 4];
            float a0 = ap[0] + bf2f((ushort)(self.x & 0xffffu));
            float a1 = ap[1] + bf2f((ushort)(self.x >> 16));
            float a2 = ap[2] + bf2f((ushort)(self.y & 0xffffu));
            float a3 = ap[3] + bf2f((ushort)(self.y >> 16));
            uint2 o;
            o.x = pk2(a0 * dv, a1 * dv);
            o.y = pk2(a2 * dv, a3 * dv);
            ob[(size_t)n * 8 + ll] = o;
        }
    }
}

// ------- MFMA GEMM layer 1: h1g = bf16(relu(Mg@W1 + b1) * dinv) ------------
// A and out are group-major [(K/32)][N][32] / [4][N][32].
template <int K>
__global__ __launch_bounds__(256) void k_gemm_f(const ushort* __restrict__ A,
                                                const ushort* __restrict__ Wt,
                                                const int* __restrict__ fflag,
                                                const float* __restrict__ dinv,
                                                const void* __restrict__ bias,
                                                ushort* __restrict__ out) {
    int ff = *fflag;
    int wave = threadIdx.x >> 6;
    int lane = threadIdx.x & 63;
    int m16 = lane & 15;
    int q = lane >> 4;
    int rowbase = blockIdx.x * 64 + wave * 16;
    int arow = min(rowbase + m16, N_NODES - 1);

    f32x4 acc[8];
#pragma unroll
    for (int t = 0; t < 8; t++) acc[t] = (f32x4){0.f, 0.f, 0.f, 0.f};
#pragma unroll
    for (int kc = 0; kc < K; kc += 32) {
        bf8 a = *(const bf8*)(A + ((size_t)(kc >> 5) * N_NODES + arow) * 32 + q * 8);
#pragma unroll
        for (int t = 0; t < 8; t++) {
            bf8 b = *(const bf8*)(Wt + (size_t)(t * 16 + m16) * K + kc + q * 8);
            acc[t] = __builtin_amdgcn_mfma_f32_16x16x32_bf16(a, b, acc[t], 0, 0, 0);
        }
    }
    float dv[4];
    int rowok[4];
#pragma unroll
    for (int r = 0; r < 4; r++) {
        int row = rowbase + q * 4 + r;
        rowok[r] = (row < N_NODES);
        dv[r] = rowok[r] ? dinv[row] : 1.f;
    }
#pragma unroll
    for (int t = 0; t < 8; t++) {
        int col = t * 16 + m16;
        float bv = loadf(bias, col, ff);
        ushort* og = out + (size_t)(col >> 5) * N_NODES * 32 + (col & 31);
#pragma unroll
        for (int r = 0; r < 4; r++) {
            int row = rowbase + q * 4 + r;
            if (rowok[r]) {
                float v = fmaxf(acc[t][r] + bv, 0.f) * dv[r];
                og[(size_t)row * 32] = f2bf(v);
            }
        }
    }
}

// ------- MFMA GEMM layer 2 + fused mean-pool (bias deferred to MLP) --------
// A is group-major [4][N][32].
__global__ __launch_bounds__(256) void k_gemm_pool(const ushort* __restrict__ A,
                                                   const ushort* __restrict__ Wt,
                                                   const void* __restrict__ batch,
                                                   const int* __restrict__ iflag,
                                                   float* __restrict__ gsum) {
    const int K = HID;
    int wide = *iflag;
    int tid = threadIdx.x;
    int wave = tid >> 6;
    int lane = tid & 63;
    int m16 = lane & 15;
    int q = lane >> 4;
    int rowbase = blockIdx.x * 64 + wave * 16;
    int arow = min(rowbase + m16, N_NODES - 1);

    __shared__ float sacc[64][HID];
    __shared__ int sbg[64];

    if (tid < 64) {
        int n = blockIdx.x * 64 + tid;
        int g = (n < N_NODES) ? (int)batch_at(batch, n, wide) : -1;
        sbg[tid] = (g < 0 || g >= N_GRAPHS) ? -1 : g;
    }
    f32x4 acc[8];
#pragma unroll
    for (int t = 0; t < 8; t++) acc[t] = (f32x4){0.f, 0.f, 0.f, 0.f};
#pragma unroll
    for (int kc = 0; kc < K; kc += 32) {
        bf8 a = *(const bf8*)(A + ((size_t)(kc >> 5) * N_NODES + arow) * 32 + q * 8);
#pragma unroll
        for (int t = 0; t < 8; t++) {
            bf8 b = *(const bf8*)(Wt + (size_t)(t * 16 + m16) * K + kc + q * 8);
            acc[t] = __builtin_amdgcn_mfma_f32_16x16x32_bf16(a, b, acc[t], 0, 0, 0);
        }
    }
#pragma unroll
    for (int t = 0; t < 8; t++) {
        int col = t * 16 + m16;
#pragma unroll
        for (int r = 0; r < 4; r++) {
            int rl = wave * 16 + q * 4 + r;
            int row = rowbase + q * 4 + r;
            sacc[rl][col] = (row < N_NODES) ? acc[t][r] : 0.f;
        }
    }
    __syncthreads();
    int col = tid & 127;
    int half = tid >> 7;
    int gcur = -1;
    float a = 0.f;
    for (int r = half * 32; r < half * 32 + 32; r++) {
        int g = sbg[r];
        if (g != gcur) {
            if (gcur >= 0) atomicAdd(&gsum[gcur * HID + col], a);
            a = 0.f;
            gcur = g;
        }
        a += sacc[r][col];
    }
    if (gcur >= 0) atomicAdd(&gsum[gcur * HID + col], a);
}

// -------- MLP head: out = relu((gsum/cnt + b2)@Wm1+bm1)@Wm2 + bm2 ; f32 -----
__global__ void k_mlp(const float* __restrict__ gsum, const void* __restrict__ batch,
                      const int* __restrict__ iflag, const void* __restrict__ b2,
                      const void* __restrict__ Wm1, const void* __restrict__ bm1,
                      const void* __restrict__ Wm2, const void* __restrict__ bm2,
                      const int* __restrict__ fflag, float* __restrict__ out) {
    int ff = *fflag;
    int wide = *iflag;
    int gr = blockIdx.x;
    int c = threadIdx.x;
    int lo = 0, hi = N_NODES;
    while (lo < hi) { int m = (lo + hi) >> 1; if (batch_at(batch, m, wide) < (i64)gr) lo = m + 1; else hi = m; }
    int s = lo;
    lo = s; hi = N_NODES;
    while (lo < hi) { int m = (lo + hi) >> 1; if (batch_at(batch, m, wide) < (i64)(gr + 1)) lo = m + 1; else hi = m; }
    float cnt = (float)(lo - s);

    __shared__ float sg[HID];
    __shared__ float r0[HID], r1[HID];
    sg[c] = gsum[gr * HID + c] / fmaxf(cnt, 1.0f) + loadf(b2, c, ff);
    __syncthreads();
    float acc = loadf(bm1, c, ff);
#pragma unroll 8
    for (int k = 0; k < HID; k++) acc += sg[k] * loadf(Wm1, k * HID + c, ff);
    float hid = fmaxf(acc, 0.f);
    r0[c] = hid * loadf(Wm2, c * OUT_C + 0, ff);
    r1[c] = hid * loadf(Wm2, c * OUT_C + 1, ff);
    __syncthreads();
    for (int off = 64; off > 0; off >>= 1) {
        if (c < off) { r0[c] += r0[c + off]; r1[c] += r1[c + off]; }
        __syncthreads();
    }
    if (c == 0) {
        out[gr * OUT_C + 0] = r0[0] + loadf(bm2, 0, ff);
        out[gr * OUT_C + 1] = r1[0] + loadf(bm2, 1, ff);
    }
}

// ---------------- launch ----------------

extern "C" void kernel_launch(void* const* d_in, const int* in_sizes, int n_in,
                              void* d_out, int out_size, void* d_ws, size_t ws_size,
                              hipStream_t stream) {
    const void* x     = d_in[0];
    const void* ei    = d_in[1];
    const void* batch = d_in[2];
    const void* W1  = d_in[3];
    const void* b1  = d_in[4];
    const void* W2  = d_in[5];
    const void* b2  = d_in[6];
    const void* Wm1 = d_in[7];
    const void* bm1 = d_in[8];
    const void* Wm2 = d_in[9];
    const void* bm2 = d_in[10];

    char* p = (char*)d_ws;
    auto alloc = [&](size_t bytes) {
        char* r = p;
        p += (bytes + 255) & ~(size_t)255;
        return r;
    };
    int*    iflag  = (int*)alloc(4);
    int*    fflag  = (int*)alloc(4);
    int*    deg    = (int*)alloc(N_NODES * 4);
    int*    bcnt   = (int*)alloc(NBUCK * 4);
    uint*   bmem   = (uint*)alloc((size_t)NBUCK * BCAP * 4);
    float*  dinv   = (float*)alloc(N_NODES * 4);
    ushort* Wt1    = (ushort*)alloc(IN_C * HID * 2);
    ushort* Wt2    = (ushort*)alloc(HID * HID * 2);
    ushort* Y1g    = (ushort*)alloc((size_t)N_NODES * IN_C * 2);   // [2][N][32]
    ushort* Mg     = (ushort*)alloc((size_t)N_NODES * IN_C * 2);   // [2][N][32]
    ushort* h1g    = (ushort*)alloc((size_t)N_NODES * HID * 2);    // [4][N][32]
    ushort* N2g    = (ushort*)alloc((size_t)N_NODES * HID * 2);    // [4][N][32]
    float*  gbuf   = (float*)alloc(N_GRAPHS * HID * 4);

    k_init<<<256, 256, 0, stream>>>(
        (const uint*)batch, (const uint*)x, deg, bcnt, gbuf, iflag, fflag);
    k_deg<<<1024, 256, 0, stream>>>(ei, iflag, fflag, W1, W2, Wt1, Wt2, deg);
    k_prep<<<512, 256, 0, stream>>>(deg, x, fflag, dinv, Y1g);
    k_binA<<<(N_EDGES + ECH - 1) / ECH, 1024, 0, stream>>>(ei, iflag, bcnt, bmem);

    // layer 1: Mg = dinv*(LDS-scatter gather Y1 + self), 2 groups
    k_agg<1><<<NBUCK * 2, 256, 0, stream>>>(Y1g, dinv, bcnt, bmem, Mg);
    // h1g = relu(Mg@W1 + b1)*dinv, group-major out
    k_gemm_f<IN_C><<<(N_NODES + 63) / 64, 256, 0, stream>>>(Mg, Wt1, fflag, dinv, b1, h1g);
    // layer 2: N2g = dinv*(LDS-scatter gather h1 + self), 4 groups
    k_agg<2><<<NBUCK * 4, 256, 0, stream>>>(h1g, dinv, bcnt, bmem, N2g);
    // pool(N2g@W2) fused
    k_gemm_pool<<<(N_NODES + 63) / 64, 256, 0, stream>>>(N2g, Wt2, batch, iflag, gbuf);

    k_mlp<<<N_GRAPHS, HID, 0, stream>>>(gbuf, batch, iflag, b2, Wm1, bm1, Wm2, bm2, fflag, (float*)d_out);
}

// Round 8
// 205.851 us; speedup vs baseline: 5.8272x; 5.8272x over previous
//
#include <hip/hip_runtime.h>
#include <stdint.h>

#define N_NODES 50000
#define N_EDGES 800000
#define IN_C 64
#define HID 128
#define OUT_C 2
#define N_GRAPHS 64
#define NBUCK 196                    // ceil(N_NODES/256) buckets of 256 nodes
#define BCAP 6144                    // bucket capacity (mean 4096, sd ~64)
#define ECH 4096                     // edges per binA chunk (16 KB packed stage)

typedef long long i64;
typedef __attribute__((ext_vector_type(8))) short bf8;    // 8 bf16 = 4 VGPRs
typedef __attribute__((ext_vector_type(4))) float f32x4;  // MFMA C/D frag

__device__ __forceinline__ float bf2f(ushort h) {
    return __uint_as_float(((uint)h) << 16);
}
__device__ __forceinline__ ushort f2bf(float f) {
    uint x = __float_as_uint(f);
    uint r = x + 0x7fffu + ((x >> 16) & 1u);   // RNE
    return (ushort)(r >> 16);
}
__device__ __forceinline__ float loadf(const void* p, size_t i, int bf) {
    return bf ? bf2f(((const ushort*)p)[i]) : ((const float*)p)[i];
}
__device__ __forceinline__ int clampi(int v, int lo, int hi) {
    return min(max(v, lo), hi);
}
__device__ __forceinline__ int edge_src(const void* ei, int e, int wide) {
    return wide ? (int)((const i64*)ei)[e] : ((const int*)ei)[e];
}
__device__ __forceinline__ int edge_dst(const void* ei, int e, int wide) {
    return wide ? (int)((const i64*)ei)[N_EDGES + e] : ((const int*)ei)[N_EDGES + e];
}
__device__ __forceinline__ i64 batch_at(const void* b, int i, int wide) {
    return wide ? ((const i64*)b)[i] : (i64)((const int*)b)[i];
}
__device__ __forceinline__ void bacc4(float* a, uint2 u) {
    a[0] += bf2f((ushort)(u.x & 0xffffu)); a[1] += bf2f((ushort)(u.x >> 16));
    a[2] += bf2f((ushort)(u.y & 0xffffu)); a[3] += bf2f((ushort)(u.y >> 16));
}
__device__ __forceinline__ uint pk2(float lo, float hi) {
    return ((uint)f2bf(hi) << 16) | (uint)f2bf(lo);
}

// ---- R24: per-block dtype probe (replaces k_init's flag kernel).
// One wave reduces 256 x-dwords + 100 batch-hi-dwords via shfl; ~0.5 µs. ----
__device__ __forceinline__ void block_probe(const uint* __restrict__ braw,
                                            const uint* __restrict__ xraw,
                                            int& wide, int& ff) {
    __shared__ int s_if, s_ff;
    if (threadIdx.x < 64) {
        int l = threadIdx.x;
        uint io = 0u;
        int fc = 0;
#pragma unroll
        for (int j = 0; j < 4; j++) {
            int t = l + 64 * j;
            if (t < 100) io |= braw[25001 + 2 * t];
            uint e = (xraw[t] >> 7) & 0xFFu;
            fc += (e >= 100u && e <= 140u) ? 1 : 0;
        }
#pragma unroll
        for (int off = 32; off > 0; off >>= 1) {
            io |= (uint)__shfl_down((int)io, off);
            fc += __shfl_down(fc, off);
        }
        if (l == 0) {
            s_if = (io == 0u) ? 1 : 0;    // 1 = int64, 0 = int32
            s_ff = (fc >= 192) ? 1 : 0;   // 1 = bf16,  0 = f32
        }
    }
    __syncthreads();
    wide = s_if;
    ff = s_ff;
}

// ---- binA: bin edges by dst>>8 via LDS-sorted staging; contiguous runs.
// Edges packed into ONE uint (src:16 | dlocal:8 | bucket:8). Blocks 0..95
// also transpose W1/W2 (t<256); block 96 converts b1 -> f32. ----
__global__ __launch_bounds__(1024) void k_binA(const void* __restrict__ ei,
                                               const uint* __restrict__ braw,
                                               const uint* __restrict__ xraw,
                                               const void* __restrict__ W1,
                                               const void* __restrict__ W2,
                                               const void* __restrict__ b1,
                                               ushort* __restrict__ Wt1,
                                               ushort* __restrict__ Wt2,
                                               float* __restrict__ b1f,
                                               int* __restrict__ bcnt,
                                               uint* __restrict__ bmem) {
    int wide, ff;
    block_probe(braw, xraw, wide, ff);
    int t = threadIdx.x;
    if (t < 256 && blockIdx.x < (IN_C * HID + HID * HID) / 256) {
        int idx = blockIdx.x * 256 + t;
        if (idx < IN_C * HID) {
            int k = idx >> 7, n = idx & 127;
            Wt1[n * IN_C + k] = f2bf(loadf(W1, idx, ff));
        } else {
            int j = idx - IN_C * HID;
            int k = j >> 7, n = j & 127;
            Wt2[n * HID + k] = f2bf(loadf(W2, j, ff));
        }
    }
    if (blockIdx.x == 96 && t < HID) b1f[t] = loadf(b1, t, ff);

    __shared__ int cnt[NBUCK];
    __shared__ int obase[NBUCK];
    __shared__ int run[NBUCK];
    __shared__ int gbase[NBUCK];
    __shared__ int sc[256];
    __shared__ uint stage[ECH];
    int e0 = blockIdx.x * ECH;
    int m = min(ECH, N_EDGES - e0);
    for (int i = t; i < NBUCK; i += 1024) cnt[i] = 0;
    __syncthreads();
    for (int i = t; i < m; i += 1024) {
        int d = edge_dst(ei, e0 + i, wide);
        atomicAdd(&cnt[d >> 8], 1);
    }
    __syncthreads();
    int cv = (t < NBUCK) ? cnt[t] : 0;
    if (t < 256) sc[t] = cv;
    __syncthreads();
    for (int off = 1; off < 256; off <<= 1) {
        int v = (t >= off && t < 256) ? sc[t - off] : 0;
        __syncthreads();
        if (t < 256) sc[t] += v;
        __syncthreads();
    }
    if (t < NBUCK) {
        int ex = sc[t] - cv;
        obase[t] = ex;
        run[t] = ex;
        gbase[t] = (cv > 0) ? atomicAdd(&bcnt[t], cv) : 0;
    }
    __syncthreads();
    for (int i = t; i < m; i += 1024) {
        int s = edge_src(ei, e0 + i, wide);
        int d = edge_dst(ei, e0 + i, wide);
        int slot = atomicAdd(&run[d >> 8], 1);
        uint pr = (uint)clampi(s, 0, N_NODES - 1) |
                  ((uint)(d & 255) << 16) | ((uint)(d >> 8) << 24);
        stage[clampi(slot, 0, ECH - 1)] = pr;
    }
    __syncthreads();
    for (int i = t; i < m; i += 1024) {
        uint pr = stage[i];
        int b = (int)(pr >> 24);
        int pos = gbase[b] + (i - obase[b]);
        if (pos < BCAP) bmem[(size_t)b * BCAP + pos] = pr;
    }
}

// ---- binB: per-bucket LDS counting-sort -> offs/csr(ushort)/dinv,
// self-scans bcnt, writes Y1 = bf16(dinv*x) group-major [2][N][32]. ----
__global__ __launch_bounds__(1024) void k_binB(const uint* __restrict__ bmem,
                                               const int* __restrict__ bcnt,
                                               const void* __restrict__ x,
                                               const uint* __restrict__ braw,
                                               int* __restrict__ offs,
                                               ushort* __restrict__ csr,
                                               float* __restrict__ dinv,
                                               ushort* __restrict__ Y1) {
    int wide, ff;
    block_probe(braw, (const uint*)x, wide, ff);
    int b = blockIdx.x;
    int t = threadIdx.x;
    int node0 = b << 8;
    __shared__ int sc[256];
    __shared__ int degl[256];
    __shared__ int run[256];
    __shared__ float sdinv[256];
    __shared__ int sbase, scnt;
    __shared__ ushort stage[BCAP];
    int v = (t < NBUCK) ? bcnt[t] : 0;
    if (t < 256) sc[t] = v;
    __syncthreads();
    for (int off = 1; off < 256; off <<= 1) {
        int u = (t >= off && t < 256) ? sc[t - off] : 0;
        __syncthreads();
        if (t < 256) sc[t] += u;
        __syncthreads();
    }
    if (t == b) {
        int c = clampi(v, 0, BCAP);
        scnt = c;
        sbase = clampi(sc[t] - v, 0, N_EDGES - c);
    }
    if (t < 256) degl[t] = 0;
    __syncthreads();
    int cnt = scnt;
    int base = sbase;
    for (int i = t; i < cnt; i += 1024) {
        uint pr = bmem[(size_t)b * BCAP + i];
        atomicAdd(&degl[(pr >> 16) & 255], 1);
    }
    __syncthreads();
    int dv = (t < 256) ? degl[t] : 0;
    if (t < 256) sc[t] = dv;
    __syncthreads();
    for (int off = 1; off < 256; off <<= 1) {
        int u = (t >= off && t < 256) ? sc[t - off] : 0;
        __syncthreads();
        if (t < 256) sc[t] += u;
        __syncthreads();
    }
    if (t < 256) {
        int ex = sc[t] - dv;
        run[t] = ex;
        float di = rsqrtf((float)(dv + 1));
        sdinv[t] = di;
        int n = node0 + t;
        if (n < N_NODES) { offs[n] = base + ex; dinv[n] = di; }
    }
    if (b == 0 && t == 0) offs[N_NODES] = N_EDGES;
    __syncthreads();
    for (int i = t; i < cnt; i += 1024) {
        uint pr = bmem[(size_t)b * BCAP + i];
        int slot = atomicAdd(&run[(pr >> 16) & 255], 1);
        stage[clampi(slot, 0, BCAP - 1)] = (ushort)(pr & 0xFFFFu);
    }
    __syncthreads();
    for (int i = t; i < cnt; i += 1024) csr[base + i] = stage[i];
    for (int idx = t; idx < 256 * (IN_C / 4); idx += 1024) {
        int nl = idx >> 4, c4 = (idx & 15) * 4;
        int nn = node0 + nl;
        if (nn < N_NODES) {
            float x0, x1, x2, x3;
            if (ff) {
                ushort4 u = *(const ushort4*)((const ushort*)x + (size_t)nn * IN_C + c4);
                x0 = bf2f(u.x); x1 = bf2f(u.y); x2 = bf2f(u.z); x3 = bf2f(u.w);
            } else {
                float4 vv = *(const float4*)((const float*)x + (size_t)nn * IN_C + c4);
                x0 = vv.x; x1 = vv.y; x2 = vv.z; x3 = vv.w;
            }
            float di = sdinv[nl];
            ushort4 o;
            o.x = f2bf(x0 * di); o.y = f2bf(x1 * di);
            o.z = f2bf(x2 * di); o.w = f2bf(x3 * di);
            int g = c4 >> 5;     // group-major write
            *(ushort4*)(Y1 + ((size_t)g * N_NODES + nn) * 32 + (c4 & 31)) = o;
        }
    }
}

// ---- channel-grouped gather. Group-major src/out [(1<<SHIFT)][N][32].
// group = blockIdx & mask: with XCD round-robin each XCD touches one
// group's contiguous 3.2 MB region. 8 lanes/node, uint2 loads. ----
template <int SHIFT>
__global__ __launch_bounds__(256) void k_aggS(const ushort* __restrict__ src,
                                              const float* __restrict__ dinv,
                                              const int* __restrict__ offs,
                                              const ushort* __restrict__ csr,
                                              ushort* __restrict__ out) {
    int g = blockIdx.x & ((1 << SHIFT) - 1);
    int chunk = blockIdx.x >> SHIFT;
    int n = (chunk * 256 + (int)threadIdx.x) >> 3;
    int lane = threadIdx.x & 7;
    if (n >= N_NODES) return;
    const uint2* s2 = (const uint2*)(src + (size_t)g * N_NODES * 32);
    size_t rb = (size_t)n * 8 + lane;
    float a[4];
    {
        uint2 su = s2[rb];                     // self contribution
        a[0] = bf2f((ushort)(su.x & 0xffffu)); a[1] = bf2f((ushort)(su.x >> 16));
        a[2] = bf2f((ushort)(su.y & 0xffffu)); a[3] = bf2f((ushort)(su.y >> 16));
    }
    int s = offs[n];
    int e = min(offs[n + 1], s + 4096);        // poison-replay guard
    int i = s;
    for (; i + 8 <= e; i += 8) {
        uint2 u[8];
#pragma unroll
        for (int k = 0; k < 8; k++)
            u[k] = s2[(size_t)csr[i + k] * 8 + lane];
#pragma unroll
        for (int k = 0; k < 8; k++) bacc4(a, u[k]);
    }
    for (; i < e; i++) bacc4(a, s2[(size_t)csr[i] * 8 + lane]);
    float dv = dinv[n];
    uint2 o;
    o.x = pk2(a[0] * dv, a[1] * dv);
    o.y = pk2(a[2] * dv, a[3] * dv);
    ((uint2*)(out + (size_t)g * N_NODES * 32))[rb] = o;
}

// ------- MFMA GEMM layer 1: h1g = bf16(relu(Mg@W1 + b1f) * dinv) -----------
// A and out are group-major [(K/32)][N][32] / [4][N][32]. No probe needed.
template <int K>
__global__ __launch_bounds__(256) void k_gemm_f(const ushort* __restrict__ A,
                                                const ushort* __restrict__ Wt,
                                                const float* __restrict__ dinv,
                                                const float* __restrict__ b1f,
                                                ushort* __restrict__ out) {
    int wave = threadIdx.x >> 6;
    int lane = threadIdx.x & 63;
    int m16 = lane & 15;
    int q = lane >> 4;
    int rowbase = blockIdx.x * 64 + wave * 16;
    int arow = min(rowbase + m16, N_NODES - 1);

    f32x4 acc[8];
#pragma unroll
    for (int t = 0; t < 8; t++) acc[t] = (f32x4){0.f, 0.f, 0.f, 0.f};
#pragma unroll
    for (int kc = 0; kc < K; kc += 32) {
        bf8 a = *(const bf8*)(A + ((size_t)(kc >> 5) * N_NODES + arow) * 32 + q * 8);
#pragma unroll
        for (int t = 0; t < 8; t++) {
            bf8 b = *(const bf8*)(Wt + (size_t)(t * 16 + m16) * K + kc + q * 8);
            acc[t] = __builtin_amdgcn_mfma_f32_16x16x32_bf16(a, b, acc[t], 0, 0, 0);
        }
    }
    float dv[4];
    int rowok[4];
#pragma unroll
    for (int r = 0; r < 4; r++) {
        int row = rowbase + q * 4 + r;
        rowok[r] = (row < N_NODES);
        dv[r] = rowok[r] ? dinv[row] : 1.f;
    }
#pragma unroll
    for (int t = 0; t < 8; t++) {
        int col = t * 16 + m16;
        float bv = b1f[col];
        ushort* og = out + (size_t)(col >> 5) * N_NODES * 32 + (col & 31);
#pragma unroll
        for (int r = 0; r < 4; r++) {
            int row = rowbase + q * 4 + r;
            if (rowok[r]) {
                float v = fmaxf(acc[t][r] + bv, 0.f) * dv[r];
                og[(size_t)row * 32] = f2bf(v);
            }
        }
    }
}

// ------- MFMA GEMM layer 2 + fused mean-pool (bias deferred to MLP) --------
// A is group-major [4][N][32].
__global__ __launch_bounds__(256) void k_gemm_pool(const ushort* __restrict__ A,
                                                   const ushort* __restrict__ Wt,
                                                   const void* __restrict__ batch,
                                                   const uint* __restrict__ xraw,
                                                   float* __restrict__ gsum) {
    int wide, ff;
    block_probe((const uint*)batch, xraw, wide, ff);
    const int K = HID;
    int tid = threadIdx.x;
    int wave = tid >> 6;
    int lane = tid & 63;
    int m16 = lane & 15;
    int q = lane >> 4;
    int rowbase = blockIdx.x * 64 + wave * 16;
    int arow = min(rowbase + m16, N_NODES - 1);

    __shared__ float sacc[64][HID];
    __shared__ int sbg[64];

    if (tid < 64) {
        int n = blockIdx.x * 64 + tid;
        int g = (n < N_NODES) ? (int)batch_at(batch, n, wide) : -1;
        sbg[tid] = (g < 0 || g >= N_GRAPHS) ? -1 : g;
    }
    f32x4 acc[8];
#pragma unroll
    for (int t = 0; t < 8; t++) acc[t] = (f32x4){0.f, 0.f, 0.f, 0.f};
#pragma unroll
    for (int kc = 0; kc < K; kc += 32) {
        bf8 a = *(const bf8*)(A + ((size_t)(kc >> 5) * N_NODES + arow) * 32 + q * 8);
#pragma unroll
        for (int t = 0; t < 8; t++) {
            bf8 b = *(const bf8*)(Wt + (size_t)(t * 16 + m16) * K + kc + q * 8);
            acc[t] = __builtin_amdgcn_mfma_f32_16x16x32_bf16(a, b, acc[t], 0, 0, 0);
        }
    }
#pragma unroll
    for (int t = 0; t < 8; t++) {
        int col = t * 16 + m16;
#pragma unroll
        for (int r = 0; r < 4; r++) {
            int rl = wave * 16 + q * 4 + r;
            int row = rowbase + q * 4 + r;
            sacc[rl][col] = (row < N_NODES) ? acc[t][r] : 0.f;
        }
    }
    __syncthreads();
    int col = tid & 127;
    int half = tid >> 7;
    int gcur = -1;
    float a = 0.f;
    for (int r = half * 32; r < half * 32 + 32; r++) {
        int g = sbg[r];
        if (g != gcur) {
            if (gcur >= 0) atomicAdd(&gsum[gcur * HID + col], a);
            a = 0.f;
            gcur = g;
        }
        a += sacc[r][col];
    }
    if (gcur >= 0) atomicAdd(&gsum[gcur * HID + col], a);
}

// -------- MLP head: out = relu((gsum/cnt + b2)@Wm1+bm1)@Wm2 + bm2 ; f32 -----
__global__ __launch_bounds__(128) void k_mlp(const float* __restrict__ gsum,
                      const void* __restrict__ batch, const uint* __restrict__ xraw,
                      const void* __restrict__ b2,
                      const void* __restrict__ Wm1, const void* __restrict__ bm1,
                      const void* __restrict__ Wm2, const void* __restrict__ bm2,
                      float* __restrict__ out) {
    int wide, ff;
    block_probe((const uint*)batch, xraw, wide, ff);
    int gr = blockIdx.x;
    int c = threadIdx.x;
    int lo = 0, hi = N_NODES;
    while (lo < hi) { int m = (lo + hi) >> 1; if (batch_at(batch, m, wide) < (i64)gr) lo = m + 1; else hi = m; }
    int s = lo;
    lo = s; hi = N_NODES;
    while (lo < hi) { int m = (lo + hi) >> 1; if (batch_at(batch, m, wide) < (i64)(gr + 1)) lo = m + 1; else hi = m; }
    float cnt = (float)(lo - s);

    __shared__ float sg[HID];
    __shared__ float r0[HID], r1[HID];
    sg[c] = gsum[gr * HID + c] / fmaxf(cnt, 1.0f) + loadf(b2, c, ff);
    __syncthreads();
    float acc = loadf(bm1, c, ff);
#pragma unroll 8
    for (int k = 0; k < HID; k++) acc += sg[k] * loadf(Wm1, k * HID + c, ff);
    float hid = fmaxf(acc, 0.f);
    r0[c] = hid * loadf(Wm2, c * OUT_C + 0, ff);
    r1[c] = hid * loadf(Wm2, c * OUT_C + 1, ff);
    __syncthreads();
    for (int off = 64; off > 0; off >>= 1) {
        if (c < off) { r0[c] += r0[c + off]; r1[c] += r1[c + off]; }
        __syncthreads();
    }
    if (c == 0) {
        out[gr * OUT_C + 0] = r0[0] + loadf(bm2, 0, ff);
        out[gr * OUT_C + 1] = r1[0] + loadf(bm2, 1, ff);
    }
}

// ---------------- launch ----------------

extern "C" void kernel_launch(void* const* d_in, const int* in_sizes, int n_in,
                              void* d_out, int out_size, void* d_ws, size_t ws_size,
                              hipStream_t stream) {
    const void* x     = d_in[0];
    const void* ei    = d_in[1];
    const void* batch = d_in[2];
    const void* W1  = d_in[3];
    const void* b1  = d_in[4];
    const void* W2  = d_in[5];
    const void* b2  = d_in[6];
    const void* Wm1 = d_in[7];
    const void* bm1 = d_in[8];
    const void* Wm2 = d_in[9];
    const void* bm2 = d_in[10];

    char* p = (char*)d_ws;
    auto alloc = [&](size_t bytes) {
        char* r = p;
        p += (bytes + 255) & ~(size_t)255;
        return r;
    };
    int*    bcnt   = (int*)alloc(NBUCK * 4);
    uint*   bmem   = (uint*)alloc((size_t)NBUCK * BCAP * 4);
    float*  dinv   = (float*)alloc(N_NODES * 4);
    int*    offs   = (int*)alloc((N_NODES + 1) * 4);
    ushort* csr    = (ushort*)alloc(N_EDGES * 2);
    ushort* Wt1    = (ushort*)alloc(IN_C * HID * 2);
    ushort* Wt2    = (ushort*)alloc(HID * HID * 2);
    float*  b1f    = (float*)alloc(HID * 4);
    ushort* Y1g    = (ushort*)alloc((size_t)N_NODES * IN_C * 2);   // [2][N][32]
    ushort* Mg     = (ushort*)alloc((size_t)N_NODES * IN_C * 2);   // [2][N][32]
    ushort* h1g    = (ushort*)alloc((size_t)N_NODES * HID * 2);    // [4][N][32]
    ushort* N2g    = (ushort*)alloc((size_t)N_NODES * HID * 2);    // [4][N][32]
    float*  gbuf   = (float*)alloc(N_GRAPHS * HID * 4);

    hipMemsetAsync(bcnt, 0, NBUCK * 4, stream);
    hipMemsetAsync(gbuf, 0, N_GRAPHS * HID * 4, stream);

    k_binA<<<(N_EDGES + ECH - 1) / ECH, 1024, 0, stream>>>(
        ei, (const uint*)batch, (const uint*)x, W1, W2, b1, Wt1, Wt2, b1f, bcnt, bmem);
    k_binB<<<NBUCK, 1024, 0, stream>>>(bmem, bcnt, x, (const uint*)batch,
                                       offs, csr, dinv, Y1g);

    int cpg = (N_NODES * 8 + 255) / 256;   // chunks per group (1563)
    // layer 1: Mg = dinv*(gather Y1g + self), 2 channel groups (XCD-resident)
    k_aggS<1><<<cpg * 2, 256, 0, stream>>>(Y1g, dinv, offs, csr, Mg);
    // h1g = relu(Mg@W1 + b1)*dinv, group-major out
    k_gemm_f<IN_C><<<(N_NODES + 63) / 64, 256, 0, stream>>>(Mg, Wt1, dinv, b1f, h1g);
    // layer 2: N2g = dinv*(gather h1g + self), 4 channel groups (XCD-resident)
    k_aggS<2><<<cpg * 4, 256, 0, stream>>>(h1g, dinv, offs, csr, N2g);
    // pool(N2g@W2) fused
    k_gemm_pool<<<(N_NODES + 63) / 64, 256, 0, stream>>>(N2g, Wt2, batch, (const uint*)x, gbuf);

    k_mlp<<<N_GRAPHS, 128, 0, stream>>>(gbuf, batch, (const uint*)x, b2, Wm1, bm1, Wm2, bm2, (float*)d_out);
}